// Round 6
// baseline (1704.268 us; speedup 1.0000x reference)
//
#include <hip/hip_runtime.h>

// EnsembleLayer: y[b, n*32+c] = sum_c' M[n][c][c'] * x[b, clusters[n][c']] + bias[n][c]
// where M[n] = dec_w[n] @ enc_w[n]  (fused encoder+decoder, one pass)
//
// B=131072, F=512, NC=16, CS=32, NH=16.
//
// Round-4 post-mortem: DPP broadcast regressed (215us) -- spilled M to scratch
// (+90MB HBM traffic) and added 47% VALU. It also falsified the "LDS is the
// bottleneck" model: the R3 swizzled reads are same-address broadcasts within
// each cluster (64B unique per b128 wave-inst, ~4cyc) -> LDS pipe ~27us.
// R3's 167us with all pipes <40% busy = latency/occupancy-bound (only 4
// blocks/CU resident, OccupancyPercent 37). This version: SAME R3 kernel,
// occupancy doubled -- 2048 blocks (8/CU), RPB=64, __launch_bounds__(256,8).
// VGPR=64 and LDS=18.4KB both fit 8 blocks/CU exactly.
// (Resubmitted unchanged: Round-5 bench failed with GPUAcquisitionTimeout.)

#define B_ROWS   131072
#define F        512
#define NC       16
#define CS       32
#define NH       16
#define NBLOCKS  2048
#define RPB      64    // rows per block (B_ROWS / NBLOCKS)
#define RPI      4     // rows per iteration
#define NITER    (RPB / RPI)

__global__ __launch_bounds__(256, 8)
void ensemble_kernel(const float* __restrict__ x,
                     const int*   __restrict__ clusters,
                     const float* __restrict__ enc_w,
                     const float* __restrict__ enc_b,
                     const float* __restrict__ dec_w,
                     const float* __restrict__ dec_b,
                     float*       __restrict__ out) {
    // xi tile (double-buffered), swizzled within each cluster row: value
    // xi[n*32+c] stored at slot n*32 + ((c + 4n) & 31). Within a cluster all
    // 16 lanes read the SAME 16B per k-step (broadcast, free); across the 4
    // clusters of a wave the swizzle staggers banks -> fully conflict-free.
    __shared__ float s_xi[2][RPI][F];   // 16 KB
    __shared__ int   s_tgt[F];          // s_tgt[src_col] = swizzled LDS slot

    const int t = threadIdx.x;

    // ---- build inverse-permutation target table (once per block) ----
    for (int j = t; j < F; j += 256) {
        int col = clusters[j];                 // xi position j sources x column col
        int nn = j >> 5, cc = j & 31;
        s_tgt[col] = (nn << 5) | ((cc + (nn << 2)) & 31);
    }
    __syncthreads();

    // cache my 4 scatter targets (I always load the same 4 source columns)
    const int cbase = (t & 127) << 2;
    const int tgt0 = s_tgt[cbase + 0];
    const int tgt1 = s_tgt[cbase + 1];
    const int tgt2 = s_tgt[cbase + 2];
    const int tgt3 = s_tgt[cbase + 3];

    const int n  = t >> 4;                     // my cluster
    const int c0 = (t & 15) << 1;              // my 2 output columns
    const int rhalf = t >> 7;                  // which row of a 2-row pass I load
    const int row_block = blockIdx.x * RPB;

    // per-thread walking pointers (no 64-bit mul in the loop)
    const float* xp = x + (size_t)(row_block + rhalf) * F + cbase;
    const int xioff = n << 5;
    float* op = out + (size_t)row_block * F + xioff + c0;

    // ---- issue the first tile's loads NOW; latency hides under M-compute ----
    float4 v[2];
    v[0] = *(const float4*)(xp);
    v[1] = *(const float4*)(xp + 2 * F);
    xp += RPI * F;

    // ---- compute my fused M rows + biases (registers) ----
    float m0[32], m1[32];
    #pragma unroll
    for (int i = 0; i < 32; ++i) { m0[i] = 0.f; m1[i] = 0.f; }
    float b0 = dec_b[n * CS + c0];
    float b1 = dec_b[n * CS + c0 + 1];

    for (int h = 0; h < NH; ++h) {
        const float d0 = dec_w[(n * CS + c0)     * NH + h];
        const float d1 = dec_w[(n * CS + c0 + 1) * NH + h];
        const float eb = enc_b[n * NH + h];
        b0 += d0 * eb;
        b1 += d1 * eb;
        const float4* ew = (const float4*)(enc_w + (n * NH + h) * CS);
        #pragma unroll
        for (int k = 0; k < 8; ++k) {
            float4 e = ew[k];
            m0[4*k+0] += d0 * e.x;  m1[4*k+0] += d1 * e.x;
            m0[4*k+1] += d0 * e.y;  m1[4*k+1] += d1 * e.y;
            m0[4*k+2] += d0 * e.z;  m1[4*k+2] += d1 * e.z;
            m0[4*k+3] += d0 * e.w;  m1[4*k+3] += d1 * e.w;
        }
    }

    // ---- scatter tile 0 into buffer 0 ----
    {
        float* d0p = s_xi[0][0 * 2 + rhalf];
        d0p[tgt0] = v[0].x; d0p[tgt1] = v[0].y; d0p[tgt2] = v[0].z; d0p[tgt3] = v[0].w;
        float* d1p = s_xi[0][1 * 2 + rhalf];
        d1p[tgt0] = v[1].x; d1p[tgt1] = v[1].y; d1p[tgt2] = v[1].z; d1p[tgt3] = v[1].w;
    }
    __syncthreads();

    // ---- main pipelined loop: ONE barrier per iteration ----
    for (int it = 0; it < NITER - 1; ++it) {
        const int cur = it & 1;

        // prefetch tile it+1 (consumed only by the scatter below)
        v[0] = *(const float4*)(xp);
        v[1] = *(const float4*)(xp + 2 * F);
        xp += RPI * F;

        // compute 4 rows from buffer cur: each thread 2 outputs, 64 FMAs/row
        #pragma unroll
        for (int r = 0; r < RPI; ++r) {
            float a0 = b0, a1 = b1;
            const float* xr = &s_xi[cur][r][xioff];
            #pragma unroll
            for (int k = 0; k < 8; ++k) {
                const int kk = (k + n) & 7;            // swizzled slot for c=4k..4k+3
                float4 xv = *(const float4*)(xr + (kk << 2));
                a0 += m0[4*k+0] * xv.x;  a1 += m1[4*k+0] * xv.x;
                a0 += m0[4*k+1] * xv.y;  a1 += m1[4*k+1] * xv.y;
                a0 += m0[4*k+2] * xv.z;  a1 += m1[4*k+2] * xv.z;
                a0 += m0[4*k+3] * xv.w;  a1 += m1[4*k+3] * xv.w;
            }
            *(float2*)(op + r * F) = make_float2(a0, a1);
        }
        op += RPI * F;

        // scatter prefetched tile into the other buffer
        {
            float* d0p = s_xi[cur ^ 1][0 * 2 + rhalf];
            d0p[tgt0] = v[0].x; d0p[tgt1] = v[0].y; d0p[tgt2] = v[0].z; d0p[tgt3] = v[0].w;
            float* d1p = s_xi[cur ^ 1][1 * 2 + rhalf];
            d1p[tgt0] = v[1].x; d1p[tgt1] = v[1].y; d1p[tgt2] = v[1].z; d1p[tgt3] = v[1].w;
        }
        __syncthreads();
    }

    // ---- peeled final tile: compute only ----
    {
        const int cur = (NITER - 1) & 1;
        #pragma unroll
        for (int r = 0; r < RPI; ++r) {
            float a0 = b0, a1 = b1;
            const float* xr = &s_xi[cur][r][xioff];
            #pragma unroll
            for (int k = 0; k < 8; ++k) {
                const int kk = (k + n) & 7;
                float4 xv = *(const float4*)(xr + (kk << 2));
                a0 += m0[4*k+0] * xv.x;  a1 += m1[4*k+0] * xv.x;
                a0 += m0[4*k+1] * xv.y;  a1 += m1[4*k+1] * xv.y;
                a0 += m0[4*k+2] * xv.z;  a1 += m1[4*k+2] * xv.z;
                a0 += m0[4*k+3] * xv.w;  a1 += m1[4*k+3] * xv.w;
            }
            *(float2*)(op + r * F) = make_float2(a0, a1);
        }
    }
}

extern "C" void kernel_launch(void* const* d_in, const int* in_sizes, int n_in,
                              void* d_out, int out_size, void* d_ws, size_t ws_size,
                              hipStream_t stream) {
    const float* x      = (const float*)d_in[0];
    const int*   clus   = (const int*)  d_in[1];
    const float* enc_w  = (const float*)d_in[2];
    const float* enc_b  = (const float*)d_in[3];
    const float* dec_w  = (const float*)d_in[4];
    const float* dec_b  = (const float*)d_in[5];
    float*       out    = (float*)d_out;

    ensemble_kernel<<<NBLOCKS, 256, 0, stream>>>(x, clus, enc_w, enc_b, dec_w, dec_b, out);
}

// Round 12
// 489.362 us; speedup vs baseline: 3.4826x; 3.4826x over previous
//
#include <hip/hip_runtime.h>

// EnsembleLayer: y[b, n*32+c] = sum_c' M[n][c][c'] * x[b, clusters[n][c']] + bias[n][c]
// where M[n] = dec_w[n] @ enc_w[n]  (fused encoder+decoder, one pass)
//
// B=131072, F=512, NC=16, CS=32, NH=16.
//
// Round-8 post-mortem: grid-2048 + double-buffer/single-barrier pipeline FAILED
// the post-timing determinism check (absmax 1.58 after graph replays) -- a
// marginal race in the 1-barrier WAR structure that only manifests at 8
// blocks/CU co-residency. The pipeline was measured NEUTRAL anyway (167 vs
// 170us, R3). This version: revert to the battle-tested 2-barrier single-buffer
// body (verified across the whole previous session + R0), keep ONLY the
// occupancy lever under test: grid 2048 (RPB=64), __launch_bounds__(256,4)
// unchanged so the allocator keeps emitting the proven 64-VGPR code and the
// hardware packs 8 blocks/CU on its own (VGPR=64 allows 8 waves/SIMD;
// LDS 18.4KB x 8 = 147KB <= 160KB).
// (Resubmitted unchanged: Rounds 9-11 failed with GPUAcquisitionTimeout.)

#define B_ROWS   131072
#define F        512
#define NC       16
#define CS       32
#define NH       16
#define NBLOCKS  2048
#define RPB      64    // rows per block (B_ROWS / NBLOCKS)
#define RPI      8     // rows per iteration
#define NITER    (RPB / RPI)

__global__ __launch_bounds__(256, 4)
void ensemble_kernel(const float* __restrict__ x,
                     const int*   __restrict__ clusters,
                     const float* __restrict__ enc_w,
                     const float* __restrict__ enc_b,
                     const float* __restrict__ dec_w,
                     const float* __restrict__ dec_b,
                     float*       __restrict__ out) {
    // xi tile, swizzled within each cluster row: value xi[n*32+c] stored at
    // slot n*32 + ((c + 4n) & 31) -> per-k b128 reads are same-address
    // broadcasts within a cluster and bank-staggered across the 4 clusters
    // of a wave (conflict-free).
    __shared__ float s_xi[RPI][F];
    __shared__ int   s_tgt[F];   // s_tgt[src_col] = swizzled LDS slot

    const int t = threadIdx.x;

    // ---- build inverse-permutation target table (once per block) ----
    for (int j = t; j < F; j += 256) {
        int col = clusters[j];                 // xi position j sources x column col
        int nn = j >> 5, cc = j & 31;
        s_tgt[col] = (nn << 5) | ((cc + (nn << 2)) & 31);
    }
    __syncthreads();

    // cache my 4 scatter targets (I always load the same 4 source columns)
    const int cbase = (t & 127) << 2;
    const int tgt0 = s_tgt[cbase + 0];
    const int tgt1 = s_tgt[cbase + 1];
    const int tgt2 = s_tgt[cbase + 2];
    const int tgt3 = s_tgt[cbase + 3];

    // ---- compute my fused M rows + biases (registers) ----
    // thread owns cluster n, output columns c0 and c0+1
    const int n  = t >> 4;
    const int c0 = (t & 15) << 1;

    float m0[32], m1[32];
    #pragma unroll
    for (int i = 0; i < 32; ++i) { m0[i] = 0.f; m1[i] = 0.f; }
    float b0 = dec_b[n * CS + c0];
    float b1 = dec_b[n * CS + c0 + 1];

    for (int h = 0; h < NH; ++h) {
        const float d0 = dec_w[(n * CS + c0)     * NH + h];
        const float d1 = dec_w[(n * CS + c0 + 1) * NH + h];
        const float eb = enc_b[n * NH + h];
        b0 += d0 * eb;
        b1 += d1 * eb;
        const float4* ew = (const float4*)(enc_w + (n * NH + h) * CS);
        #pragma unroll
        for (int k = 0; k < 8; ++k) {
            float4 e = ew[k];
            m0[4*k+0] += d0 * e.x;  m1[4*k+0] += d1 * e.x;
            m0[4*k+1] += d0 * e.y;  m1[4*k+1] += d1 * e.y;
            m0[4*k+2] += d0 * e.z;  m1[4*k+2] += d1 * e.z;
            m0[4*k+3] += d0 * e.w;  m1[4*k+3] += d1 * e.w;
        }
    }

    // ---- main loop: 8 rows per iteration, 2 barriers (verified structure) ----
    const int rhalf = t >> 7;                  // which of 2 rows this thread loads per pass
    const int row_block = blockIdx.x * RPB;
    const int xioff = n << 5;                  // my cluster's base slot in a xi row

    for (int it = 0; it < NITER; ++it) {
        const int r0 = row_block + it * RPI;

        // coalesced float4 loads of 8 rows (independent of LDS -> scheduled early)
        float4 v[4];
        #pragma unroll
        for (int p = 0; p < 4; ++p) {
            const float* src = x + (size_t)(r0 + p * 2 + rhalf) * F + cbase;
            v[p] = *(const float4*)src;
        }

        __syncthreads();   // previous iteration's xi reads complete

        // scatter into permuted+swizzled LDS slots
        #pragma unroll
        for (int p = 0; p < 4; ++p) {
            float* dst = s_xi[p * 2 + rhalf];
            dst[tgt0] = v[p].x;
            dst[tgt1] = v[p].y;
            dst[tgt2] = v[p].z;
            dst[tgt3] = v[p].w;
        }

        __syncthreads();

        // compute 8 rows: each thread 2 outputs, 64 FMAs/row
        #pragma unroll
        for (int r = 0; r < RPI; ++r) {
            float a0 = b0, a1 = b1;
            const float* xr = &s_xi[r][xioff];
            #pragma unroll
            for (int k = 0; k < 8; ++k) {
                const int kk = (k + n) & 7;            // swizzled slot holding c=4k..4k+3
                float4 xv = *(const float4*)(xr + (kk << 2));
                a0 += m0[4*k+0] * xv.x;  a1 += m1[4*k+0] * xv.x;
                a0 += m0[4*k+1] * xv.y;  a1 += m1[4*k+1] * xv.y;
                a0 += m0[4*k+2] * xv.z;  a1 += m1[4*k+2] * xv.z;
                a0 += m0[4*k+3] * xv.w;  a1 += m1[4*k+3] * xv.w;
            }
            float2 o = make_float2(a0, a1);
            *(float2*)(out + (size_t)(r0 + r) * F + xioff + c0) = o;
        }
    }
}

extern "C" void kernel_launch(void* const* d_in, const int* in_sizes, int n_in,
                              void* d_out, int out_size, void* d_ws, size_t ws_size,
                              hipStream_t stream) {
    const float* x      = (const float*)d_in[0];
    const int*   clus   = (const int*)  d_in[1];
    const float* enc_w  = (const float*)d_in[2];
    const float* enc_b  = (const float*)d_in[3];
    const float* dec_w  = (const float*)d_in[4];
    const float* dec_b  = (const float*)d_in[5];
    float*       out    = (float*)d_out;

    ensemble_kernel<<<NBLOCKS, 256, 0, stream>>>(x, clus, enc_w, enc_b, dec_w, dec_b, out);
}

// Round 13
// 475.255 us; speedup vs baseline: 3.5860x; 1.0297x over previous
//
#include <hip/hip_runtime.h>

// EnsembleLayer: y[b, n*32+c] = sum_c' M[n][c][c'] * x[b, clusters[n][c']] + bias[n][c]
// where M[n] = dec_w[n] @ enc_w[n]  (fused encoder+decoder, one pass)
//
// B=131072, F=512, NC=16, CS=32, NH=16.
//
// Round-12 post-mortem: grid 2048 did NOT raise residency (OccupancyPercent
// stuck at 38-39%, same as grid 1024) and cost +17us of doubled per-block
// M-setup -> occupancy-via-grid theory falsified, grid reverted to 1024.
// Standing mystery: dur 167us vs 64us HBM floor with every pipe <40% busy.
// Remaining suspect: HBM burst duty cycle (~38% = 2.4/6.3 TB/s) -- each
// iteration is a short load burst followed by drain/scatter/compute/barriers.
// This version: RPI 8->16 (NITER 16->8). Halves the per-block barrier/drain
// events and doubles the per-wave load burst (8 x b128 in flight), raising
// memory-request duty per phase. Pure parameter change inside the verified
// 2-barrier template (same dependency structure). LDS 32KB+2KB=34.8KB/block
// -> still 4 blocks/CU.

#define B_ROWS   131072
#define F        512
#define NC       16
#define CS       32
#define NH       16
#define NBLOCKS  1024
#define RPB      128   // rows per block (B_ROWS / NBLOCKS)
#define RPI      16    // rows per iteration (was 8)
#define NITER    (RPB / RPI)

__global__ __launch_bounds__(256, 4)
void ensemble_kernel(const float* __restrict__ x,
                     const int*   __restrict__ clusters,
                     const float* __restrict__ enc_w,
                     const float* __restrict__ enc_b,
                     const float* __restrict__ dec_w,
                     const float* __restrict__ dec_b,
                     float*       __restrict__ out) {
    // xi tile, swizzled within each cluster row: value xi[n*32+c] stored at
    // slot n*32 + ((c + 4n) & 31) -> per-k b128 reads are same-address
    // broadcasts within a cluster and bank-staggered across the 4 clusters
    // of a wave (conflict-free).
    __shared__ float s_xi[RPI][F];   // 32 KB
    __shared__ int   s_tgt[F];       // s_tgt[src_col] = swizzled LDS slot

    const int t = threadIdx.x;

    // ---- build inverse-permutation target table (once per block) ----
    for (int j = t; j < F; j += 256) {
        int col = clusters[j];                 // xi position j sources x column col
        int nn = j >> 5, cc = j & 31;
        s_tgt[col] = (nn << 5) | ((cc + (nn << 2)) & 31);
    }
    __syncthreads();

    // cache my 4 scatter targets (I always load the same 4 source columns)
    const int cbase = (t & 127) << 2;
    const int tgt0 = s_tgt[cbase + 0];
    const int tgt1 = s_tgt[cbase + 1];
    const int tgt2 = s_tgt[cbase + 2];
    const int tgt3 = s_tgt[cbase + 3];

    // ---- compute my fused M rows + biases (registers) ----
    // thread owns cluster n, output columns c0 and c0+1
    const int n  = t >> 4;
    const int c0 = (t & 15) << 1;

    float m0[32], m1[32];
    #pragma unroll
    for (int i = 0; i < 32; ++i) { m0[i] = 0.f; m1[i] = 0.f; }
    float b0 = dec_b[n * CS + c0];
    float b1 = dec_b[n * CS + c0 + 1];

    for (int h = 0; h < NH; ++h) {
        const float d0 = dec_w[(n * CS + c0)     * NH + h];
        const float d1 = dec_w[(n * CS + c0 + 1) * NH + h];
        const float eb = enc_b[n * NH + h];
        b0 += d0 * eb;
        b1 += d1 * eb;
        const float4* ew = (const float4*)(enc_w + (n * NH + h) * CS);
        #pragma unroll
        for (int k = 0; k < 8; ++k) {
            float4 e = ew[k];
            m0[4*k+0] += d0 * e.x;  m1[4*k+0] += d1 * e.x;
            m0[4*k+1] += d0 * e.y;  m1[4*k+1] += d1 * e.y;
            m0[4*k+2] += d0 * e.z;  m1[4*k+2] += d1 * e.z;
            m0[4*k+3] += d0 * e.w;  m1[4*k+3] += d1 * e.w;
        }
    }

    // ---- main loop: 16 rows per iteration, 2 barriers (verified structure) ----
    const int rhalf = t >> 7;                  // which of 2 rows this thread loads per pass
    const int row_block = blockIdx.x * RPB;
    const int xioff = n << 5;                  // my cluster's base slot in a xi row

    for (int it = 0; it < NITER; ++it) {
        const int r0 = row_block + it * RPI;

        // coalesced float4 loads of 16 rows (long burst, independent of LDS)
        float4 v[8];
        #pragma unroll
        for (int p = 0; p < 8; ++p) {
            const float* src = x + (size_t)(r0 + p * 2 + rhalf) * F + cbase;
            v[p] = *(const float4*)src;
        }

        __syncthreads();   // previous iteration's xi reads complete

        // scatter into permuted+swizzled LDS slots
        #pragma unroll
        for (int p = 0; p < 8; ++p) {
            float* dst = s_xi[p * 2 + rhalf];
            dst[tgt0] = v[p].x;
            dst[tgt1] = v[p].y;
            dst[tgt2] = v[p].z;
            dst[tgt3] = v[p].w;
        }

        __syncthreads();

        // compute 16 rows: each thread 2 outputs, 64 FMAs/row
        #pragma unroll
        for (int r = 0; r < RPI; ++r) {
            float a0 = b0, a1 = b1;
            const float* xr = &s_xi[r][xioff];
            #pragma unroll
            for (int k = 0; k < 8; ++k) {
                const int kk = (k + n) & 7;            // swizzled slot holding c=4k..4k+3
                float4 xv = *(const float4*)(xr + (kk << 2));
                a0 += m0[4*k+0] * xv.x;  a1 += m1[4*k+0] * xv.x;
                a0 += m0[4*k+1] * xv.y;  a1 += m1[4*k+1] * xv.y;
                a0 += m0[4*k+2] * xv.z;  a1 += m1[4*k+2] * xv.z;
                a0 += m0[4*k+3] * xv.w;  a1 += m1[4*k+3] * xv.w;
            }
            float2 o = make_float2(a0, a1);
            *(float2*)(out + (size_t)(r0 + r) * F + xioff + c0) = o;
        }
    }
}

extern "C" void kernel_launch(void* const* d_in, const int* in_sizes, int n_in,
                              void* d_out, int out_size, void* d_ws, size_t ws_size,
                              hipStream_t stream) {
    const float* x      = (const float*)d_in[0];
    const int*   clus   = (const int*)  d_in[1];
    const float* enc_w  = (const float*)d_in[2];
    const float* enc_b  = (const float*)d_in[3];
    const float* dec_w  = (const float*)d_in[4];
    const float* dec_b  = (const float*)d_in[5];
    float*       out    = (float*)d_out;

    ensemble_kernel<<<NBLOCKS, 256, 0, stream>>>(x, clus, enc_w, enc_b, dec_w, dec_b, out);
}